// Round 17
// baseline (242.889 us; speedup 1.0000x reference)
//
#include <hip/hip_runtime.h>
#include <hip/hip_bf16.h>

typedef __bf16 bf16;
typedef __attribute__((ext_vector_type(8))) __bf16 bf16x8;
typedef __attribute__((ext_vector_type(4))) __bf16 bf16x4;
typedef __attribute__((ext_vector_type(4))) float f32x4;
typedef __attribute__((ext_vector_type(16))) float f32x16;
typedef __attribute__((ext_vector_type(8))) int i32x8;

#define AS1 __attribute__((address_space(1)))
#define AS3 __attribute__((address_space(3)))

#define QSCALE 0.09016844f   // log2(e)/16: folded softmax scale -> epilogue uses raw exp2

__device__ inline int pk_fp8x4(float a, float b, float c, float d) {
    int r = __builtin_amdgcn_cvt_pk_fp8_f32(a, b, 0, false);   // bytes 0,1
    r = __builtin_amdgcn_cvt_pk_fp8_f32(c, d, r, true);        // bytes 2,3
    return r;
}

// 32B fragment read from swizzled LDS: two 16B granules, XOR applied per-granule
__device__ inline i32x8 lds_read32(const char* base, int off, int swz) {
    int4 lo = *(const int4*)(base + (off ^ swz));
    int4 hi = *(const int4*)(base + ((off + 16) ^ swz));
    i32x8 r = {lo.x, lo.y, lo.z, lo.w, hi.x, hi.y, hi.z, hi.w};
    return r;
}

// ---------------- weights fp32 -> bf16 + bias concat (one launch) ----------------
__global__ void cvt_w4b(const float* __restrict__ a0, const float* __restrict__ a1,
                        const float* __restrict__ a2, const float* __restrict__ a3,
                        bf16* __restrict__ o,
                        const float* __restrict__ bq, const float* __restrict__ bk,
                        const float* __restrict__ bv, float* __restrict__ bqkv) {
    int idx = blockIdx.x * 256 + threadIdx.x;       // grid 256 -> 65536 float4s
    const float* srcs[4] = {a0, a1, a2, a3};
    float4 v = ((const float4*)srcs[idx >> 14])[idx & 16383];
    bf16x4 r; r[0] = (bf16)v.x; r[1] = (bf16)v.y; r[2] = (bf16)v.z; r[3] = (bf16)v.w;
    ((bf16x4*)o)[idx] = r;
    if (blockIdx.x == 0) {
        int t = threadIdx.x;
        bqkv[t] = bq[t]; bqkv[256 + t] = bk[t]; bqkv[512 + t] = bv[t];
    }
}

// ---------------- GroupNorm stats: one block per (b,g) ----------------
__global__ void gn_stats(const float* __restrict__ x, float* __restrict__ musd) {
    const int bg = blockIdx.x;
    const float4* p = (const float4*)(x + (long)bg * 32768);
    float s = 0.f, ss = 0.f;
    for (int i = threadIdx.x; i < 8192; i += 256) {
        float4 v = p[i];
        s  += v.x + v.y + v.z + v.w;
        ss += v.x*v.x + v.y*v.y + v.z*v.z + v.w*v.w;
    }
    for (int o = 32; o; o >>= 1) { s += __shfl_down(s, o); ss += __shfl_down(ss, o); }
    __shared__ float rs[4], rss[4];
    if ((threadIdx.x & 63) == 0) { rs[threadIdx.x >> 6] = s; rss[threadIdx.x >> 6] = ss; }
    __syncthreads();
    if (threadIdx.x == 0) {
        s  = rs[0] + rs[1] + rs[2] + rs[3];
        ss = rss[0] + rss[1] + rss[2] + rss[3];
        float mu  = s * (1.f / 32768.f);
        float var = ss * (1.f / 32768.f) - mu * mu;
        musd[bg * 2]     = mu;
        musd[bg * 2 + 1] = rsqrtf(var + 1e-5f);
    }
}

// ---------------- GroupNorm apply + transpose: x[b,c,i] -> hT[b,i,c] bf16 ----------------
__global__ void gn_apply_t(const float* __restrict__ x, const float* __restrict__ musd,
                           const float* __restrict__ gw, const float* __restrict__ gb,
                           bf16* __restrict__ hT) {
    const int b  = blockIdx.x >> 6;
    const int i0 = (blockIdx.x & 63) << 6;
    __shared__ bf16 tile[256][65];
    const int lane = threadIdx.x & 63, wv = threadIdx.x >> 6;
    const long xb = (long)b * (256L * 4096);
    for (int r = 0; r < 64; ++r) {
        int c = wv * 64 + r;
        int g = c >> 3;
        float mu   = musd[(b * 32 + g) * 2];
        float rstd = musd[(b * 32 + g) * 2 + 1];
        float v = x[xb + (long)c * 4096 + i0 + lane];
        tile[c][lane] = (bf16)((v - mu) * rstd * gw[c] + gb[c]);
    }
    __syncthreads();
    for (int it = 0; it < 8; ++it) {
        int q  = it * 256 + threadIdx.x;
        int il = q >> 5;
        int c8 = (q & 31) << 3;
        bf16x8 v;
        #pragma unroll
        for (int e = 0; e < 8; ++e) v[e] = tile[c8 + e][il];
        *(bf16x8*)(&hT[((long)b * 4096 + i0 + il) * 256 + c8]) = v;
    }
}

// ---------------- BT-GEMM (128x128, 4 waves): C[m,n] = alpha*sum_k A[m,k]B[n,k] ----------------
// QK8OUT: blocks with n0<512 store fp8 to q8[z][m][n]; q channels (col<256) pre-scaled by QSCALE.
template<int BIAS_MODE /*0 none,1 row,2 col*/, bool RESID, typename OutT, bool QK8OUT = false>
__launch_bounds__(256)
__global__ void gemm_bt(const bf16* __restrict__ A, const bf16* __restrict__ B,
                        OutT* __restrict__ C,
                        const float* __restrict__ bias, const float* __restrict__ resid,
                        unsigned char* __restrict__ q8,
                        int M, int N, int K, int lda, int ldb, int ldc,
                        long sA, long sB, long sC, long sR, float alpha) {
    __shared__ __align__(1024) char lds[32768];
    const int z = blockIdx.z;
    A += (long)z * sA; B += (long)z * sB; C += (long)z * sC;
    if (QK8OUT) q8 += (long)z * (4096L * 512);
    const float* Rp = resid + (RESID ? (long)z * sR : 0);

    const int m0 = blockIdx.y * 128;
    const int n0 = blockIdx.x * 128;
    const int lane = threadIdx.x & 63;
    const int wv = threadIdx.x >> 6;
    const int wr = wv >> 1, wc = wv & 1;

    f32x4 acc[4][4];
    #pragma unroll
    for (int i = 0; i < 4; ++i)
        #pragma unroll
        for (int j = 0; j < 4; ++j) acc[i][j] = f32x4{0.f, 0.f, 0.f, 0.f};

    char* ldsA = lds;
    char* ldsB = lds + 16384;

    for (int k0 = 0; k0 < K; k0 += 64) {
        #pragma unroll
        for (int c = 0; c < 4; ++c) {
            int chunk  = wv * 4 + c;
            int ldsOff = chunk * 1024;
            int myOff  = ldsOff + lane * 16;
            int row    = myOff >> 7;
            int colB   = (myOff & 127) ^ ((row & 7) << 4);
            const char* srcA = (const char*)(A + (long)(m0 + row) * lda + k0) + colB;
            __builtin_amdgcn_global_load_lds((const AS1 void*)srcA,
                                             (AS3 void*)(ldsA + ldsOff), 16, 0, 0);
            const char* srcB = (const char*)(B + (long)(n0 + row) * ldb + k0) + colB;
            __builtin_amdgcn_global_load_lds((const AS1 void*)srcB,
                                             (AS3 void*)(ldsB + ldsOff), 16, 0, 0);
        }
        __syncthreads();
        #pragma unroll
        for (int kk = 0; kk < 2; ++kk) {
            bf16x8 aF[4], bF[4];
            const int kb = kk * 64 + (lane >> 4) * 16;
            #pragma unroll
            for (int mf = 0; mf < 4; ++mf) {
                int row = wr * 64 + mf * 16 + (lane & 15);
                aF[mf] = *(const bf16x8*)(ldsA + row * 128 + (kb ^ ((row & 7) << 4)));
            }
            #pragma unroll
            for (int nf = 0; nf < 4; ++nf) {
                int row = wc * 64 + nf * 16 + (lane & 15);
                bF[nf] = *(const bf16x8*)(ldsB + row * 128 + (kb ^ ((row & 7) << 4)));
            }
            #pragma unroll
            for (int mf = 0; mf < 4; ++mf)
                #pragma unroll
                for (int nf = 0; nf < 4; ++nf)
                    acc[mf][nf] = __builtin_amdgcn_mfma_f32_16x16x32_bf16(
                        aF[mf], bF[nf], acc[mf][nf], 0, 0, 0);
        }
        __syncthreads();
    }

    const bool fp8blk = QK8OUT && (n0 < 512);
    const bool qblk   = QK8OUT && (n0 < 256);      // uniform: q channels get QSCALE
    #pragma unroll
    for (int mf = 0; mf < 4; ++mf) {
        #pragma unroll
        for (int nf = 0; nf < 4; ++nf) {
            int col   = n0 + wc * 64 + nf * 16 + (lane & 15);
            int rbase = m0 + wr * 64 + mf * 16 + (lane >> 4) * 4;
            float cb = (BIAS_MODE == 2) ? bias[col] : 0.f;
            #pragma unroll
            for (int e = 0; e < 4; ++e) {
                int row = rbase + e;
                float v = acc[mf][nf][e] * alpha;
                if (BIAS_MODE == 1) v += bias[row];
                if (BIAS_MODE == 2) v += cb;
                if (fp8blk) {
                    float vq = qblk ? v * QSCALE : v;
                    q8[(long)row * 512 + col] =
                        (unsigned char)__builtin_amdgcn_cvt_pk_fp8_f32(vq, vq, 0, false);
                } else {
                    long off = (long)row * ldc + col;
                    if (RESID) v += Rp[off];
                    C[off] = (OutT)v;
                }
            }
        }
    }
}

// ---------------- QK GEMM, MX-FP8 (scale=1.0): B(q) full-K resident + A(k) BK=64 dbuf -------
// q pre-scaled by log2e/16 -> acc = S*log2e/16; epilogue = raw exp2 (1 VALU) + fp8 byte store
// at compile-time offsets. qk8[z][i][0:256]=q', [256:512]=k. part[z][jblk][i] fp32.
__launch_bounds__(256)
__global__ void gemm_qk_exp(const unsigned char* __restrict__ qk8,
                            unsigned char* __restrict__ P, float* __restrict__ part) {
    __shared__ __align__(1024) char lds[49152];   // B[32K] | A0[8K] | A1[8K]; epi reuses [0,19456)
    const int bid  = blockIdx.x;
    const long z   = bid & 7;                      // batch, pinned to XCD
    const int idx  = bid >> 3;
    const int xt   = idx & 31;                     // i-tile
    const int y    = idx >> 5;                     // j-tile
    const unsigned char* Q = qk8 + z * (4096L * 512);
    P += z * (4096L * 4096); part += z * (32L * 4096);
    const int m0 = y * 128;       // j (k rows, A-operand)
    const int n0 = xt * 128;      // i (q rows, B-operand)

    const int lane = threadIdx.x & 63;
    const int wv = threadIdx.x >> 6;
    const int wr = wv >> 1, wc = wv & 1;
    const int l31 = lane & 31;
    const int q5  = lane >> 5;

    char* ldsB  = lds;            // [128 rows][256B], swizzle col^((row&7)<<4)
    char* ldsA0 = lds + 32768;    // [128 rows][64B],  swizzle col^(((row>>1)&3)<<4)

    // stage B full-K once: 32 chunks (1KB = 4 rows x 256B), 8 per wave
    #pragma unroll
    for (int t = 0; t < 8; ++t) {
        int c    = wv * 8 + t;
        int row  = c * 4 + (lane >> 4);
        int colS = ((lane & 15) * 16) ^ ((row & 7) << 4);
        const char* src = (const char*)(Q + (long)(n0 + row) * 512 + colS);
        __builtin_amdgcn_global_load_lds((const AS1 void*)src,
                                         (AS3 void*)(ldsB + c * 1024), 16, 0, 0);
    }
    // stage one A BK=64 slice: 8 chunks (1KB = 16 rows x 64B), 2 per wave
    auto stageA = [&](char* dst, int k0) {
        #pragma unroll
        for (int t = 0; t < 2; ++t) {
            int c    = wv * 2 + t;
            int row  = c * 16 + (lane >> 2);
            int colB = ((lane & 3) * 16) ^ (((lane >> 3) & 3) << 4);
            const char* src = (const char*)(Q + (long)(m0 + row) * 512 + 256 + k0) + colB;
            __builtin_amdgcn_global_load_lds((const AS1 void*)src,
                                             (AS3 void*)(dst + c * 1024), 16, 0, 0);
        }
    };
    stageA(ldsA0, 0);

    f32x16 acc[2][2];
    #pragma unroll
    for (int i = 0; i < 2; ++i)
        #pragma unroll
        for (int j = 0; j < 2; ++j)
            #pragma unroll
            for (int e = 0; e < 16; ++e) acc[i][j][e] = 0.f;

    __syncthreads();
    #pragma unroll
    for (int ks = 0; ks < 4; ++ks) {
        if (ks < 3) stageA(lds + 32768 + (((ks & 1) ^ 1) * 8192), (ks + 1) * 64);
        const char* Ab2 = lds + 32768 + (ks & 1) * 8192;
        i32x8 aF[2], bF[2];
        #pragma unroll
        for (int mi = 0; mi < 2; ++mi) {
            int row = wr * 64 + mi * 32 + l31;
            aF[mi] = lds_read32(Ab2, row * 64 + q5 * 32, ((row >> 1) & 3) << 4);
        }
        #pragma unroll
        for (int ni = 0; ni < 2; ++ni) {
            int row = wc * 64 + ni * 32 + l31;
            bF[ni] = lds_read32(ldsB, row * 256 + ks * 64 + q5 * 32, (row & 7) << 4);
        }
        #pragma unroll
        for (int mi = 0; mi < 2; ++mi)
            #pragma unroll
            for (int ni = 0; ni < 2; ++ni)
                acc[mi][ni] = __builtin_amdgcn_mfma_scale_f32_32x32x64_f8f6f4(
                    aF[mi], bF[ni], acc[mi][ni], 0, 0,
                    0, 0x7f7f7f7f, 0, 0x7f7f7f7f);
        __syncthreads();
    }

    // epilogue: exp2, column sums, fp8 byte stores at imm offsets, int4 copy-out
    unsigned char* pt8 = (unsigned char*)lds;   // [128][144] (16B-aligned row stride)
    float* cs = (float*)(lds + 18432);          // [2][128]
    float s2[2] = {0.f, 0.f};
    #pragma unroll
    for (int mi = 0; mi < 2; ++mi) {
        #pragma unroll
        for (int ni = 0; ni < 2; ++ni) {
            int col = wc * 64 + ni * 32 + l31;
            unsigned char* pb = pt8 + (wr * 64 + mi * 32 + q5 * 4) * 144 + col;
            #pragma unroll
            for (int rg = 0; rg < 16; ++rg) {
                const int rl = (rg & 3) + 8 * (rg >> 2);   // compile-time
                float ev = exp2f(acc[mi][ni][rg]);
                s2[ni] += ev;
                pb[rl * 144] =
                    (unsigned char)__builtin_amdgcn_cvt_pk_fp8_f32(ev, ev, 0, false);
            }
        }
    }
    s2[0] += __shfl_xor(s2[0], 32);
    s2[1] += __shfl_xor(s2[1], 32);
    if (lane < 32) {
        cs[wr * 128 + wc * 64 + l31]      = s2[0];
        cs[wr * 128 + wc * 64 + 32 + l31] = s2[1];
    }
    __syncthreads();
    if (threadIdx.x < 128)
        part[y * 4096 + n0 + threadIdx.x] = cs[threadIdx.x] + cs[128 + threadIdx.x];
    #pragma unroll
    for (int it = 0; it < 4; ++it) {
        int qd  = it * 256 + threadIdx.x;     // 1024 chunks of 16 fp8
        int row = qd >> 3;
        int c16 = (qd & 7) << 4;
        int4 w = *(const int4*)(pt8 + row * 144 + c16);
        *(int4*)(&P[(long)(m0 + row) * 4096 + n0 + c16]) = w;
    }
}

// ---------------- fused: rl4k[i] = 4096/colsum[i]; vS[c,i] = v[c,i]*rl4k[i] (FP8) ----------------
__global__ void rl_vscale(const float* __restrict__ part, const bf16* __restrict__ qkvT,
                          unsigned char* __restrict__ vS) {
    const long z = blockIdx.y;
    const int i0 = blockIdx.x * 64;
    __shared__ float psum[4][64];
    __shared__ float rlv[64];
    __shared__ bf16 t[256][72];          // [c][i], holds v*rl*4096 (~v)
    const int tid = threadIdx.x;
    {
        int col = tid & 63, grp = tid >> 6;
        float s = 0.f;
        #pragma unroll
        for (int p = 0; p < 8; ++p)
            s += part[z * (32L * 4096) + (grp * 8 + p) * 4096 + i0 + col];
        psum[grp][col] = s;
    }
    __syncthreads();
    if (tid < 64) rlv[tid] = 4096.f / (psum[0][tid] + psum[1][tid] + psum[2][tid] + psum[3][tid]);
    __syncthreads();
    #pragma unroll
    for (int it = 0; it < 8; ++it) {
        int q = it * 256 + tid;
        int r = q >> 5;                   // i within tile
        int c8 = (q & 31) << 3;
        bf16x8 v = *(const bf16x8*)(qkvT + (z * 4096 + i0 + r) * 768 + 512 + c8);
        float sc = rlv[r];
        #pragma unroll
        for (int e = 0; e < 8; ++e) t[c8 + e][r] = (bf16)((float)v[e] * sc);
    }
    __syncthreads();
    #pragma unroll
    for (int it = 0; it < 8; ++it) {
        int q = it * 256 + tid;
        int c = q >> 3;
        int i8 = (q & 7) << 3;
        float f[8];
        #pragma unroll
        for (int e = 0; e < 8; ++e) f[e] = (float)t[c][i8 + e];
        int2 w;
        w.x = pk_fp8x4(f[0], f[1], f[2], f[3]);
        w.y = pk_fp8x4(f[4], f[5], f[6], f[7]);
        *(int2*)(vS + z * (4096L * 256) + (long)c * 4096 + i0 + i8) = w;
    }
}

// ---------------- PV GEMM, MX-FP8 (scale=1.0): 128j x 256c, split-K=2, BK=64, dbuf ----------
// grid (x=zz, y=j-tile): XCD = linear%8 = zz&7 -> each XCD's j-tiles share one vS slice (L2).
__launch_bounds__(512)
__global__ void gemm_pv(const unsigned char* __restrict__ Pg,
                        const unsigned char* __restrict__ vSg,
                        bf16* __restrict__ pvp) {
    // buffer = A[8K] | B[16K] = 24KB; dbuf @0 and @24576
    __shared__ __align__(1024) char lds[49152];
    const int zz = blockIdx.x;                    // batch*2 + ks
    const int zb = zz >> 1, ks = zz & 1;
    const char* Ab = (const char*)Pg  + (long)zb * (4096L * 4096) + ks * 2048;
    const char* Bb = (const char*)vSg + (long)zb * (4096L * 256)  + ks * 2048;
    bf16* C = pvp + (long)zz * (4096L * 256);

    const int m0 = blockIdx.y * 128;      // j
    const int lane = threadIdx.x & 63;
    const int wv = threadIdx.x >> 6;
    const int wr = wv >> 2, wc = wv & 3;
    const int l31 = lane & 31;
    const int q5  = lane >> 5;

    f32x16 acc[2][2];
    #pragma unroll
    for (int i = 0; i < 2; ++i)
        #pragma unroll
        for (int j = 0; j < 2; ++j)
            #pragma unroll
            for (int e = 0; e < 16; ++e) acc[i][j][e] = 0.f;

    auto stage = [&](char* dst, int k0) {
        #pragma unroll
        for (int t = 0; t < 3; ++t) {
            int c    = wv * 3 + t;                                   // 0..23
            int colB = ((lane & 3) * 16) ^ (((lane >> 3) & 3) << 4);
            if (c < 8) {                                             // A: 128 rows j
                int row = c * 16 + (lane >> 2);
                const char* src = Ab + (long)(m0 + row) * 4096 + k0 + colB;
                __builtin_amdgcn_global_load_lds((const AS1 void*)src,
                                                 (AS3 void*)(dst + c * 1024), 16, 0, 0);
            } else {                                                 // B: 256 rows c
                int row = (c - 8) * 16 + (lane >> 2);
                const char* src = Bb + (long)row * 4096 + k0 + colB;
                __builtin_amdgcn_global_load_lds((const AS1 void*)src,
                                                 (AS3 void*)(dst + c * 1024), 16, 0, 0);
            }
        }
    };
    auto compute = [&](const char* buf) {
        i32x8 aF[2], bF[2];
        #pragma unroll
        for (int mi = 0; mi < 2; ++mi) {
            int row = wr * 64 + mi * 32 + l31;
            aF[mi] = lds_read32(buf, row * 64 + q5 * 32, ((row >> 1) & 3) << 4);
        }
        #pragma unroll
        for (int ni = 0; ni < 2; ++ni) {
            int row = wc * 64 + ni * 32 + l31;
            bF[ni] = lds_read32(buf + 8192, row * 64 + q5 * 32, ((row >> 1) & 3) << 4);
        }
        #pragma unroll
        for (int mi = 0; mi < 2; ++mi)
            #pragma unroll
            for (int ni = 0; ni < 2; ++ni)
                acc[mi][ni] = __builtin_amdgcn_mfma_scale_f32_32x32x64_f8f6f4(
                    aF[mi], bF[ni], acc[mi][ni], 0, 0,
                    0, 0x7f7f7f7f, 0, 0x7f7f7f7f);
    };

    stage(lds, 0);
    __syncthreads();
    for (int ks2 = 0; ks2 < 32; ++ks2) {
        char* cur = lds + (ks2 & 1) * 24576;
        char* nxt = lds + ((ks2 & 1) ^ 1) * 24576;
        if (ks2 < 31) stage(nxt, (ks2 + 1) * 64);
        compute(cur);
        __syncthreads();
    }

    #pragma unroll
    for (int mi = 0; mi < 2; ++mi) {
        #pragma unroll
        for (int ni = 0; ni < 2; ++ni) {
            int col = wc * 64 + ni * 32 + l31;
            int rb  = m0 + wr * 64 + mi * 32 + q5 * 4;
            #pragma unroll
            for (int rg = 0; rg < 16; ++rg) {
                int rl = (rg & 3) + 8 * (rg >> 2);
                C[(long)(rb + rl) * 256 + col] = (bf16)acc[mi][ni][rg];
            }
        }
    }
}

// ---------------- split-K reduce: 2 bf16 slabs -> bf16, x 2^-12 (undo rl*4096) ----------------
__global__ void reduce2(const bf16* __restrict__ p, bf16* __restrict__ out) {
    const long z = blockIdx.y;
    int idx = blockIdx.x * 256 + threadIdx.x;     // 131072 bf16x8 chunks per batch
    const bf16x8* base = (const bf16x8*)p + z * 2 * 131072;
    bf16x8 a = base[idx], b = base[idx + 131072];
    bf16x8 o;
    #pragma unroll
    for (int e = 0; e < 8; ++e)
        o[e] = (bf16)(((float)a[e] + (float)b[e]) * (1.f / 4096.f));
    ((bf16x8*)out)[z * 131072 + idx] = o;
}

extern "C" void kernel_launch(void* const* d_in, const int* in_sizes, int n_in,
                              void* d_out, int out_size, void* d_ws, size_t ws_size,
                              hipStream_t stream) {
    const float* x   = (const float*)d_in[0];
    const float* gnw = (const float*)d_in[1];
    const float* gnb = (const float*)d_in[2];
    const float* wq  = (const float*)d_in[3];
    const float* bq  = (const float*)d_in[4];
    const float* wk  = (const float*)d_in[5];
    const float* bk  = (const float*)d_in[6];
    const float* wv  = (const float*)d_in[7];
    const float* bv  = (const float*)d_in[8];
    const float* wo  = (const float*)d_in[9];
    const float* bo  = (const float*)d_in[10];
    float* out = (float*)d_out;

    char* ws = (char*)d_ws;
    size_t off = 0;
    auto alloc = [&](size_t b) { char* p = ws + off; off += (b + 255) & ~(size_t)255; return p; };

    const long NC = 4096L * 256;          // per-batch [N,C] elems
    const long ST = 4096L * 768;          // per-batch qkvT stride
    bf16* qkvT = (bf16*)alloc(8 * ST * 2);                         // 48 MiB (only v-slab written)
    bf16* h2T  = (bf16*)alloc(8 * NC * 2);                         // 16 MiB
    bf16* wall = (bf16*)alloc(4 * 65536 * 2);                      // 0.5 MiB
    float* bqkv = (float*)alloc(768 * 4);
    float* musd = (float*)alloc(256 * 2 * 4);
    unsigned char* qk8 = (unsigned char*)alloc(8 * 4096L * 512);   // 16 MiB
    float* part = (float*)alloc(8 * 32L * 4096 * 4);               // 4 MiB
    unsigned char* vS = (unsigned char*)alloc(8 * NC);             // 8 MiB
    bf16*  pvp  = (bf16*)alloc(16 * NC * 2);                       // 32 MiB (8 batches x 2 splits)
    unsigned char* P  = (unsigned char*)alloc(8 * 4096L * 4096);   // 128 MiB (exp(S) fp8)
    bf16* hT = (bf16*)P;            // alias: hT (16 MiB) dead before P is written
    bf16* wob = wall + 196608;

    cvt_w4b<<<256, 256, 0, stream>>>(wq, wk, wv, wo, wall, bq, bk, bv, bqkv);
    gn_stats<<<256, 256, 0, stream>>>(x, musd);
    gn_apply_t<<<512, 256, 0, stream>>>(x, musd, gnw, gnb, hT);

    // qkvT v-slab (bf16) + qk8 q,k slabs (fp8; q pre-scaled by log2e/16)
    gemm_bt<2, false, bf16, true><<<dim3(6, 32, 8), 256, 0, stream>>>(
        hT, wall, qkvT, bqkv, nullptr, qk8,
        4096, 768, 256, 256, 256, 768, NC, 0, ST, 0, 1.f);

    // attention: single pass over all 8 batches
    gemm_qk_exp<<<8192, 256, 0, stream>>>(qk8, P, part);
    rl_vscale<<<dim3(64, 8), 256, 0, stream>>>(part, qkvT, vS);
    gemm_pv<<<dim3(16, 32), 512, 0, stream>>>(P, vS, pvp);
    reduce2<<<dim3(512, 8), 256, 0, stream>>>(pvp, h2T);

    // out[o,j] = x[o,j] + bo[o] + sum_c wo[o,c] h2T[j,c]
    gemm_bt<1, true, float><<<dim3(32, 2, 8), 256, 0, stream>>>(
        wob, h2T, out, bo, x, nullptr, 256, 4096, 256, 256, 256, 4096, 0, NC, NC, NC, 1.f);
}

// Round 18
// 235.810 us; speedup vs baseline: 1.0300x; 1.0300x over previous
//
#include <hip/hip_runtime.h>
#include <hip/hip_bf16.h>

typedef __bf16 bf16;
typedef __attribute__((ext_vector_type(8))) __bf16 bf16x8;
typedef __attribute__((ext_vector_type(4))) __bf16 bf16x4;
typedef __attribute__((ext_vector_type(4))) float f32x4;
typedef __attribute__((ext_vector_type(16))) float f32x16;
typedef __attribute__((ext_vector_type(8))) int i32x8;

#define AS1 __attribute__((address_space(1)))
#define AS3 __attribute__((address_space(3)))

__device__ inline int pk_fp8x4(float a, float b, float c, float d) {
    int r = __builtin_amdgcn_cvt_pk_fp8_f32(a, b, 0, false);   // bytes 0,1
    r = __builtin_amdgcn_cvt_pk_fp8_f32(c, d, r, true);        // bytes 2,3
    return r;
}

__device__ inline unsigned char fp8_1(float v) {
    return (unsigned char)(__builtin_amdgcn_cvt_pk_fp8_f32(v, v, 0, false) & 0xff);
}

// 32B fragment read from swizzled LDS: two 16B granules, XOR applied per-granule
__device__ inline i32x8 lds_read32(const char* base, int off, int swz) {
    int4 lo = *(const int4*)(base + (off ^ swz));
    int4 hi = *(const int4*)(base + ((off + 16) ^ swz));
    i32x8 r = {lo.x, lo.y, lo.z, lo.w, hi.x, hi.y, hi.z, hi.w};
    return r;
}

// ---------------- weights fp32 -> bf16 + bias concat (one launch) ----------------
__global__ void cvt_w4b(const float* __restrict__ a0, const float* __restrict__ a1,
                        const float* __restrict__ a2, const float* __restrict__ a3,
                        bf16* __restrict__ o,
                        const float* __restrict__ bq, const float* __restrict__ bk,
                        const float* __restrict__ bv, float* __restrict__ bqkv) {
    int idx = blockIdx.x * 256 + threadIdx.x;       // grid 256 -> 65536 float4s
    const float* srcs[4] = {a0, a1, a2, a3};
    float4 v = ((const float4*)srcs[idx >> 14])[idx & 16383];
    bf16x4 r; r[0] = (bf16)v.x; r[1] = (bf16)v.y; r[2] = (bf16)v.z; r[3] = (bf16)v.w;
    ((bf16x4*)o)[idx] = r;
    if (blockIdx.x == 0) {
        int t = threadIdx.x;
        bqkv[t] = bq[t]; bqkv[256 + t] = bk[t]; bqkv[512 + t] = bv[t];
    }
}

// ---------------- GroupNorm stats: one block per (b,g) ----------------
__global__ void gn_stats(const float* __restrict__ x, float* __restrict__ musd) {
    const int bg = blockIdx.x;
    const float4* p = (const float4*)(x + (long)bg * 32768);
    float s = 0.f, ss = 0.f;
    for (int i = threadIdx.x; i < 8192; i += 256) {
        float4 v = p[i];
        s  += v.x + v.y + v.z + v.w;
        ss += v.x*v.x + v.y*v.y + v.z*v.z + v.w*v.w;
    }
    for (int o = 32; o; o >>= 1) { s += __shfl_down(s, o); ss += __shfl_down(ss, o); }
    __shared__ float rs[4], rss[4];
    if ((threadIdx.x & 63) == 0) { rs[threadIdx.x >> 6] = s; rss[threadIdx.x >> 6] = ss; }
    __syncthreads();
    if (threadIdx.x == 0) {
        s  = rs[0] + rs[1] + rs[2] + rs[3];
        ss = rss[0] + rss[1] + rss[2] + rss[3];
        float mu  = s * (1.f / 32768.f);
        float var = ss * (1.f / 32768.f) - mu * mu;
        musd[bg * 2]     = mu;
        musd[bg * 2 + 1] = rsqrtf(var + 1e-5f);
    }
}

// ---------------- GroupNorm apply + transpose: x[b,c,i] -> hT[b,i,c] bf16 ----------------
__global__ void gn_apply_t(const float* __restrict__ x, const float* __restrict__ musd,
                           const float* __restrict__ gw, const float* __restrict__ gb,
                           bf16* __restrict__ hT) {
    const int b  = blockIdx.x >> 6;
    const int i0 = (blockIdx.x & 63) << 6;
    __shared__ bf16 tile[256][65];
    const int lane = threadIdx.x & 63, wv = threadIdx.x >> 6;
    const long xb = (long)b * (256L * 4096);
    for (int r = 0; r < 64; ++r) {
        int c = wv * 64 + r;
        int g = c >> 3;
        float mu   = musd[(b * 32 + g) * 2];
        float rstd = musd[(b * 32 + g) * 2 + 1];
        float v = x[xb + (long)c * 4096 + i0 + lane];
        tile[c][lane] = (bf16)((v - mu) * rstd * gw[c] + gb[c]);
    }
    __syncthreads();
    for (int it = 0; it < 8; ++it) {
        int q  = it * 256 + threadIdx.x;
        int il = q >> 5;
        int c8 = (q & 31) << 3;
        bf16x8 v;
        #pragma unroll
        for (int e = 0; e < 8; ++e) v[e] = tile[c8 + e][il];
        *(bf16x8*)(&hT[((long)b * 4096 + i0 + il) * 256 + c8]) = v;
    }
}

// ---------------- BT-GEMM (128x128, 4 waves): C[m,n] = alpha*sum_k A[m,k]B[n,k] ----------------
// QK8OUT: blocks with n0<512 store fp8 to q8[z][m][n] (from f32 acc) and SKIP the bf16 C store.
template<int BIAS_MODE /*0 none,1 row,2 col*/, bool RESID, typename OutT, bool QK8OUT = false>
__launch_bounds__(256)
__global__ void gemm_bt(const bf16* __restrict__ A, const bf16* __restrict__ B,
                        OutT* __restrict__ C,
                        const float* __restrict__ bias, const float* __restrict__ resid,
                        unsigned char* __restrict__ q8,
                        int M, int N, int K, int lda, int ldb, int ldc,
                        long sA, long sB, long sC, long sR, float alpha) {
    __shared__ __align__(1024) char lds[32768];
    const int z = blockIdx.z;
    A += (long)z * sA; B += (long)z * sB; C += (long)z * sC;
    if (QK8OUT) q8 += (long)z * (4096L * 512);
    const float* Rp = resid + (RESID ? (long)z * sR : 0);

    const int m0 = blockIdx.y * 128;
    const int n0 = blockIdx.x * 128;
    const int lane = threadIdx.x & 63;
    const int wv = threadIdx.x >> 6;
    const int wr = wv >> 1, wc = wv & 1;

    f32x4 acc[4][4];
    #pragma unroll
    for (int i = 0; i < 4; ++i)
        #pragma unroll
        for (int j = 0; j < 4; ++j) acc[i][j] = f32x4{0.f, 0.f, 0.f, 0.f};

    char* ldsA = lds;
    char* ldsB = lds + 16384;

    for (int k0 = 0; k0 < K; k0 += 64) {
        #pragma unroll
        for (int c = 0; c < 4; ++c) {
            int chunk  = wv * 4 + c;
            int ldsOff = chunk * 1024;
            int myOff  = ldsOff + lane * 16;
            int row    = myOff >> 7;
            int colB   = (myOff & 127) ^ ((row & 7) << 4);
            const char* srcA = (const char*)(A + (long)(m0 + row) * lda + k0) + colB;
            __builtin_amdgcn_global_load_lds((const AS1 void*)srcA,
                                             (AS3 void*)(ldsA + ldsOff), 16, 0, 0);
            const char* srcB = (const char*)(B + (long)(n0 + row) * ldb + k0) + colB;
            __builtin_amdgcn_global_load_lds((const AS1 void*)srcB,
                                             (AS3 void*)(ldsB + ldsOff), 16, 0, 0);
        }
        __syncthreads();
        #pragma unroll
        for (int kk = 0; kk < 2; ++kk) {
            bf16x8 aF[4], bF[4];
            const int kb = kk * 64 + (lane >> 4) * 16;
            #pragma unroll
            for (int mf = 0; mf < 4; ++mf) {
                int row = wr * 64 + mf * 16 + (lane & 15);
                aF[mf] = *(const bf16x8*)(ldsA + row * 128 + (kb ^ ((row & 7) << 4)));
            }
            #pragma unroll
            for (int nf = 0; nf < 4; ++nf) {
                int row = wc * 64 + nf * 16 + (lane & 15);
                bF[nf] = *(const bf16x8*)(ldsB + row * 128 + (kb ^ ((row & 7) << 4)));
            }
            #pragma unroll
            for (int mf = 0; mf < 4; ++mf)
                #pragma unroll
                for (int nf = 0; nf < 4; ++nf)
                    acc[mf][nf] = __builtin_amdgcn_mfma_f32_16x16x32_bf16(
                        aF[mf], bF[nf], acc[mf][nf], 0, 0, 0);
        }
        __syncthreads();
    }

    const bool fp8blk = QK8OUT && (n0 < 512);
    #pragma unroll
    for (int mf = 0; mf < 4; ++mf) {
        #pragma unroll
        for (int nf = 0; nf < 4; ++nf) {
            int col   = n0 + wc * 64 + nf * 16 + (lane & 15);
            int rbase = m0 + wr * 64 + mf * 16 + (lane >> 4) * 4;
            float cb = (BIAS_MODE == 2) ? bias[col] : 0.f;
            #pragma unroll
            for (int e = 0; e < 4; ++e) {
                int row = rbase + e;
                float v = acc[mf][nf][e] * alpha;
                if (BIAS_MODE == 1) v += bias[row];
                if (BIAS_MODE == 2) v += cb;
                if (fp8blk) {
                    q8[(long)row * 512 + col] = fp8_1(v);
                } else {
                    long off = (long)row * ldc + col;
                    if (RESID) v += Rp[off];
                    C[off] = (OutT)v;
                }
            }
        }
    }
}

// ---------------- QK GEMM, MX-FP8 (scale=1.0): B(q) full-K resident + A(k) BK=64 dbuf -------
// 32x32x64 scale-MFMA. Epilogue: exp -> fp8 DIRECT to LDS pt8[128][144]; store = pure int4 copy.
// qk8[z][i][0:256]=q, [256:512]=k. P[z][j,i] = exp(S/16) fp8; part[z][jblk][i] fp32.
__launch_bounds__(256)
__global__ void gemm_qk_exp(const unsigned char* __restrict__ qk8,
                            unsigned char* __restrict__ P, float* __restrict__ part) {
    __shared__ __align__(1024) char lds[49152];   // B[32K] | A0[8K] | A1[8K]; epi reuses [0,19456)
    const int bid  = blockIdx.x;
    const long z   = bid & 7;                      // batch, pinned to XCD
    const int idx  = bid >> 3;
    const int xt   = idx & 31;                     // i-tile
    const int y    = idx >> 5;                     // j-tile
    const unsigned char* Q = qk8 + z * (4096L * 512);
    P += z * (4096L * 4096); part += z * (32L * 4096);
    const int m0 = y * 128;       // j (k rows, A-operand)
    const int n0 = xt * 128;      // i (q rows, B-operand)

    const int lane = threadIdx.x & 63;
    const int wv = threadIdx.x >> 6;
    const int wr = wv >> 1, wc = wv & 1;
    const int l31 = lane & 31;
    const int q5  = lane >> 5;

    char* ldsB  = lds;            // [128 rows][256B], swizzle col^((row&7)<<4)
    char* ldsA0 = lds + 32768;    // [128 rows][64B],  swizzle col^(((row>>1)&3)<<4)

    // stage B full-K once: 32 chunks (1KB = 4 rows x 256B), 8 per wave
    #pragma unroll
    for (int t = 0; t < 8; ++t) {
        int c    = wv * 8 + t;
        int row  = c * 4 + (lane >> 4);
        int colS = ((lane & 15) * 16) ^ ((row & 7) << 4);
        const char* src = (const char*)(Q + (long)(n0 + row) * 512 + colS);
        __builtin_amdgcn_global_load_lds((const AS1 void*)src,
                                         (AS3 void*)(ldsB + c * 1024), 16, 0, 0);
    }
    // stage one A BK=64 slice: 8 chunks (1KB = 16 rows x 64B), 2 per wave
    auto stageA = [&](char* dst, int k0) {
        #pragma unroll
        for (int t = 0; t < 2; ++t) {
            int c    = wv * 2 + t;
            int row  = c * 16 + (lane >> 2);
            int colB = ((lane & 3) * 16) ^ (((lane >> 3) & 3) << 4);
            const char* src = (const char*)(Q + (long)(m0 + row) * 512 + 256 + k0) + colB;
            __builtin_amdgcn_global_load_lds((const AS1 void*)src,
                                             (AS3 void*)(dst + c * 1024), 16, 0, 0);
        }
    };
    stageA(ldsA0, 0);

    f32x16 acc[2][2];
    #pragma unroll
    for (int i = 0; i < 2; ++i)
        #pragma unroll
        for (int j = 0; j < 2; ++j)
            #pragma unroll
            for (int e = 0; e < 16; ++e) acc[i][j][e] = 0.f;

    __syncthreads();
    #pragma unroll
    for (int ks = 0; ks < 4; ++ks) {
        if (ks < 3) stageA(lds + 32768 + (((ks & 1) ^ 1) * 8192), (ks + 1) * 64);
        const char* Ab2 = lds + 32768 + (ks & 1) * 8192;
        i32x8 aF[2], bF[2];
        #pragma unroll
        for (int mi = 0; mi < 2; ++mi) {
            int row = wr * 64 + mi * 32 + l31;
            aF[mi] = lds_read32(Ab2, row * 64 + q5 * 32, ((row >> 1) & 3) << 4);
        }
        #pragma unroll
        for (int ni = 0; ni < 2; ++ni) {
            int row = wc * 64 + ni * 32 + l31;
            bF[ni] = lds_read32(ldsB, row * 256 + ks * 64 + q5 * 32, (row & 7) << 4);
        }
        #pragma unroll
        for (int mi = 0; mi < 2; ++mi)
            #pragma unroll
            for (int ni = 0; ni < 2; ++ni)
                acc[mi][ni] = __builtin_amdgcn_mfma_scale_f32_32x32x64_f8f6f4(
                    aF[mi], bF[ni], acc[mi][ni], 0, 0,
                    0, 0x7f7f7f7f, 0, 0x7f7f7f7f);
        __syncthreads();
    }

    // epilogue: exp, column sums, fp8 direct to LDS, int4 copy-out (32x32 C/D layout)
    unsigned char* pt8 = (unsigned char*)lds;   // [128][144] (16B-aligned row stride)
    float* cs = (float*)(lds + 18432);          // [2][128]
    float s2[2] = {0.f, 0.f};
    #pragma unroll
    for (int mi = 0; mi < 2; ++mi) {
        #pragma unroll
        for (int ni = 0; ni < 2; ++ni) {
            int col = wc * 64 + ni * 32 + l31;
            int rb  = wr * 64 + mi * 32 + q5 * 4;
            #pragma unroll
            for (int rg = 0; rg < 16; ++rg) {
                int rl = (rg & 3) + 8 * (rg >> 2);
                float ev = __expf(acc[mi][ni][rg] * 0.0625f);
                s2[ni] += ev;
                pt8[(rb + rl) * 144 + col] = fp8_1(ev);
            }
        }
    }
    s2[0] += __shfl_xor(s2[0], 32);
    s2[1] += __shfl_xor(s2[1], 32);
    if (lane < 32) {
        cs[wr * 128 + wc * 64 + l31]      = s2[0];
        cs[wr * 128 + wc * 64 + 32 + l31] = s2[1];
    }
    __syncthreads();
    if (threadIdx.x < 128)
        part[y * 4096 + n0 + threadIdx.x] = cs[threadIdx.x] + cs[128 + threadIdx.x];
    #pragma unroll
    for (int it = 0; it < 4; ++it) {
        int qd  = it * 256 + threadIdx.x;     // 1024 chunks of 16 fp8
        int row = qd >> 3;
        int c16 = (qd & 7) << 4;
        int4 w = *(const int4*)(pt8 + row * 144 + c16);
        *(int4*)(&P[(long)(m0 + row) * 4096 + n0 + c16]) = w;
    }
}

// ---------------- fused: rl4k[i] = 4096/colsum[i]; vS[c,i] = v[c,i]*rl4k[i] (FP8) ----------------
__global__ void rl_vscale(const float* __restrict__ part, const bf16* __restrict__ qkvT,
                          unsigned char* __restrict__ vS) {
    const long z = blockIdx.y;
    const int i0 = blockIdx.x * 64;
    __shared__ float psum[4][64];
    __shared__ float rlv[64];
    __shared__ bf16 t[256][72];          // [c][i], holds v*rl*4096 (~v)
    const int tid = threadIdx.x;
    {
        int col = tid & 63, grp = tid >> 6;
        float s = 0.f;
        #pragma unroll
        for (int p = 0; p < 8; ++p)
            s += part[z * (32L * 4096) + (grp * 8 + p) * 4096 + i0 + col];
        psum[grp][col] = s;
    }
    __syncthreads();
    if (tid < 64) rlv[tid] = 4096.f / (psum[0][tid] + psum[1][tid] + psum[2][tid] + psum[3][tid]);
    __syncthreads();
    #pragma unroll
    for (int it = 0; it < 8; ++it) {
        int q = it * 256 + tid;
        int r = q >> 5;                   // i within tile
        int c8 = (q & 31) << 3;
        bf16x8 v = *(const bf16x8*)(qkvT + (z * 4096 + i0 + r) * 768 + 512 + c8);
        float sc = rlv[r];
        #pragma unroll
        for (int e = 0; e < 8; ++e) t[c8 + e][r] = (bf16)((float)v[e] * sc);
    }
    __syncthreads();
    #pragma unroll
    for (int it = 0; it < 8; ++it) {
        int q = it * 256 + tid;
        int c = q >> 3;
        int i8 = (q & 7) << 3;
        float f[8];
        #pragma unroll
        for (int e = 0; e < 8; ++e) f[e] = (float)t[c][i8 + e];
        int2 w;
        w.x = pk_fp8x4(f[0], f[1], f[2], f[3]);
        w.y = pk_fp8x4(f[4], f[5], f[6], f[7]);
        *(int2*)(vS + z * (4096L * 256) + (long)c * 4096 + i0 + i8) = w;
    }
}

// ---------------- PV GEMM, MX-FP8 (scale=1.0): 128j x 256c, split-K=2, BK=64, dbuf ----------
// grid (x=zz, y=j-tile): XCD = linear%8 = zz&7 -> each XCD's j-tiles share one vS slice (L2).
__launch_bounds__(512)
__global__ void gemm_pv(const unsigned char* __restrict__ Pg,
                        const unsigned char* __restrict__ vSg,
                        bf16* __restrict__ pvp) {
    // buffer = A[8K] | B[16K] = 24KB; dbuf @0 and @24576
    __shared__ __align__(1024) char lds[49152];
    const int zz = blockIdx.x;                    // batch*2 + ks
    const int zb = zz >> 1, ks = zz & 1;
    const char* Ab = (const char*)Pg  + (long)zb * (4096L * 4096) + ks * 2048;
    const char* Bb = (const char*)vSg + (long)zb * (4096L * 256)  + ks * 2048;
    bf16* C = pvp + (long)zz * (4096L * 256);

    const int m0 = blockIdx.y * 128;      // j
    const int lane = threadIdx.x & 63;
    const int wv = threadIdx.x >> 6;
    const int wr = wv >> 2, wc = wv & 3;
    const int l31 = lane & 31;
    const int q5  = lane >> 5;

    f32x16 acc[2][2];
    #pragma unroll
    for (int i = 0; i < 2; ++i)
        #pragma unroll
        for (int j = 0; j < 2; ++j)
            #pragma unroll
            for (int e = 0; e < 16; ++e) acc[i][j][e] = 0.f;

    auto stage = [&](char* dst, int k0) {
        #pragma unroll
        for (int t = 0; t < 3; ++t) {
            int c    = wv * 3 + t;                                   // 0..23
            int colB = ((lane & 3) * 16) ^ (((lane >> 3) & 3) << 4);
            if (c < 8) {                                             // A: 128 rows j
                int row = c * 16 + (lane >> 2);
                const char* src = Ab + (long)(m0 + row) * 4096 + k0 + colB;
                __builtin_amdgcn_global_load_lds((const AS1 void*)src,
                                                 (AS3 void*)(dst + c * 1024), 16, 0, 0);
            } else {                                                 // B: 256 rows c
                int row = (c - 8) * 16 + (lane >> 2);
                const char* src = Bb + (long)row * 4096 + k0 + colB;
                __builtin_amdgcn_global_load_lds((const AS1 void*)src,
                                                 (AS3 void*)(dst + c * 1024), 16, 0, 0);
            }
        }
    };
    auto compute = [&](const char* buf) {
        i32x8 aF[2], bF[2];
        #pragma unroll
        for (int mi = 0; mi < 2; ++mi) {
            int row = wr * 64 + mi * 32 + l31;
            aF[mi] = lds_read32(buf, row * 64 + q5 * 32, ((row >> 1) & 3) << 4);
        }
        #pragma unroll
        for (int ni = 0; ni < 2; ++ni) {
            int row = wc * 64 + ni * 32 + l31;
            bF[ni] = lds_read32(buf + 8192, row * 64 + q5 * 32, ((row >> 1) & 3) << 4);
        }
        #pragma unroll
        for (int mi = 0; mi < 2; ++mi)
            #pragma unroll
            for (int ni = 0; ni < 2; ++ni)
                acc[mi][ni] = __builtin_amdgcn_mfma_scale_f32_32x32x64_f8f6f4(
                    aF[mi], bF[ni], acc[mi][ni], 0, 0,
                    0, 0x7f7f7f7f, 0, 0x7f7f7f7f);
    };

    stage(lds, 0);
    __syncthreads();
    for (int ks2 = 0; ks2 < 32; ++ks2) {
        char* cur = lds + (ks2 & 1) * 24576;
        char* nxt = lds + ((ks2 & 1) ^ 1) * 24576;
        if (ks2 < 31) stage(nxt, (ks2 + 1) * 64);
        compute(cur);
        __syncthreads();
    }

    #pragma unroll
    for (int mi = 0; mi < 2; ++mi) {
        #pragma unroll
        for (int ni = 0; ni < 2; ++ni) {
            int col = wc * 64 + ni * 32 + l31;
            int rb  = m0 + wr * 64 + mi * 32 + q5 * 4;
            #pragma unroll
            for (int rg = 0; rg < 16; ++rg) {
                int rl = (rg & 3) + 8 * (rg >> 2);
                C[(long)(rb + rl) * 256 + col] = (bf16)acc[mi][ni][rg];
            }
        }
    }
}

// ---------------- split-K reduce: 2 bf16 slabs -> bf16, x 2^-12 (undo rl*4096) ----------------
__global__ void reduce2(const bf16* __restrict__ p, bf16* __restrict__ out) {
    const long z = blockIdx.y;
    int idx = blockIdx.x * 256 + threadIdx.x;     // 131072 bf16x8 chunks per batch
    const bf16x8* base = (const bf16x8*)p + z * 2 * 131072;
    bf16x8 a = base[idx], b = base[idx + 131072];
    bf16x8 o;
    #pragma unroll
    for (int e = 0; e < 8; ++e)
        o[e] = (bf16)(((float)a[e] + (float)b[e]) * (1.f / 4096.f));
    ((bf16x8*)out)[z * 131072 + idx] = o;
}

extern "C" void kernel_launch(void* const* d_in, const int* in_sizes, int n_in,
                              void* d_out, int out_size, void* d_ws, size_t ws_size,
                              hipStream_t stream) {
    const float* x   = (const float*)d_in[0];
    const float* gnw = (const float*)d_in[1];
    const float* gnb = (const float*)d_in[2];
    const float* wq  = (const float*)d_in[3];
    const float* bq  = (const float*)d_in[4];
    const float* wk  = (const float*)d_in[5];
    const float* bk  = (const float*)d_in[6];
    const float* wv  = (const float*)d_in[7];
    const float* bv  = (const float*)d_in[8];
    const float* wo  = (const float*)d_in[9];
    const float* bo  = (const float*)d_in[10];
    float* out = (float*)d_out;

    char* ws = (char*)d_ws;
    size_t off = 0;
    auto alloc = [&](size_t b) { char* p = ws + off; off += (b + 255) & ~(size_t)255; return p; };

    const long NC = 4096L * 256;          // per-batch [N,C] elems
    const long ST = 4096L * 768;          // per-batch qkvT stride
    bf16* qkvT = (bf16*)alloc(8 * ST * 2);                         // 48 MiB (only v-slab written)
    bf16* h2T  = (bf16*)alloc(8 * NC * 2);                         // 16 MiB
    bf16* wall = (bf16*)alloc(4 * 65536 * 2);                      // 0.5 MiB
    float* bqkv = (float*)alloc(768 * 4);
    float* musd = (float*)alloc(256 * 2 * 4);
    unsigned char* qk8 = (unsigned char*)alloc(8 * 4096L * 512);   // 16 MiB
    float* part = (float*)alloc(8 * 32L * 4096 * 4);               // 4 MiB
    unsigned char* vS = (unsigned char*)alloc(8 * NC);             // 8 MiB
    bf16*  pvp  = (bf16*)alloc(16 * NC * 2);                       // 32 MiB (8 batches x 2 splits)
    unsigned char* P  = (unsigned char*)alloc(8 * 4096L * 4096);   // 128 MiB (exp(S) fp8)
    bf16* hT = (bf16*)P;            // alias: hT (16 MiB) dead before P is written
    bf16* wob = wall + 196608;

    cvt_w4b<<<256, 256, 0, stream>>>(wq, wk, wv, wo, wall, bq, bk, bv, bqkv);
    gn_stats<<<256, 256, 0, stream>>>(x, musd);
    gn_apply_t<<<512, 256, 0, stream>>>(x, musd, gnw, gnb, hT);

    // qkvT v-slab (bf16) + qk8 q,k slabs (fp8, straight from f32 acc)
    gemm_bt<2, false, bf16, true><<<dim3(6, 32, 8), 256, 0, stream>>>(
        hT, wall, qkvT, bqkv, nullptr, qk8,
        4096, 768, 256, 256, 256, 768, NC, 0, ST, 0, 1.f);

    // attention: single pass over all 8 batches
    gemm_qk_exp<<<8192, 256, 0, stream>>>(qk8, P, part);
    rl_vscale<<<dim3(64, 8), 256, 0, stream>>>(part, qkvT, vS);
    gemm_pv<<<dim3(16, 32), 512, 0, stream>>>(P, vS, pvp);
    reduce2<<<dim3(512, 8), 256, 0, stream>>>(pvp, h2T);

    // out[o,j] = x[o,j] + bo[o] + sum_c wo[o,c] h2T[j,c]
    gemm_bt<1, true, float><<<dim3(32, 2, 8), 256, 0, stream>>>(
        wob, h2T, out, bo, x, nullptr, 256, 4096, 256, 256, 256, 4096, 0, NC, NC, NC, 1.f);
}